// Round 6
// baseline (372.586 us; speedup 1.0000x reference)
//
#include <hip/hip_runtime.h>
#include <cmath>

#define EPSF 1.1920928955078125e-07f

constexpr int BB = 8192;
constexpr int MZ = 2000;
constexpr int NF = 2048;
constexpr int ROW_BLOCKS = 1024;
constexpr int ROWS_PER_BLOCK = 8;    // 1024*8 = 8192 rows
constexpr int MG_BLOCKS = 512;
constexpr int MG_ITERS = (BB * NF / 4) / (MG_BLOCKS * 256);  // 32
constexpr float W_INT = 0.1f, W_PROB = 0.3f, W_WS = 0.5f, W_MORGAN = 0.1f;
constexpr float POS_W = 5.0f;

// d_ws layout (floats):
//   pb[k][row], k=0..4 : per-row partials (5 * 8192)
//   pbm[b], b=0..511   : morgan per-block partials
constexpr int PB_STRIDE = BB;
constexpr int PBM_OFF = 5 * BB;

// LDS-only barrier: does NOT drain vmcnt, so global prefetch loads stay in
// flight across it (unlike __syncthreads, which emits s_waitcnt vmcnt(0)).
__device__ inline void ldsBarrier() {
  asm volatile("s_waitcnt lgkmcnt(0)" ::: "memory");
  __builtin_amdgcn_s_barrier();
  asm volatile("" ::: "memory");
}

__device__ inline float waveReduce(float v) {
#pragma unroll
  for (int off = 32; off > 0; off >>= 1) v += __shfl_down(v, off, 64);
  return v;
}

__device__ inline double waveReduceD(double v) {
#pragma unroll
  for (int off = 32; off > 0; off >>= 1) v += __shfl_down(v, off, 64);
  return v;
}

// natives: v_exp_f32 / v_log_f32 — ~1ulp, threshold is 1.9e-2
__device__ inline float bceFast(float x, float y) {
  const float em = __expf(-fabsf(x));
  return fmaxf(x, 0.f) - x * y + __logf(1.f + em);
}

struct RowData {
  float4 pi0, pi1, pl0, pl1, ti0, ti1, tp0, tp1;
};

__device__ inline RowData zeroRow() {
  RowData d;
  const float4 z = make_float4(0.f, 0.f, 0.f, 0.f);
  d.pi0 = z; d.pi1 = z; d.pl0 = z; d.pl1 = z;
  d.ti0 = z; d.ti1 = z; d.tp0 = z; d.tp1 = z;
  return d;
}

__device__ inline RowData loadRow(long base, int i0,
                                  const float* __restrict__ pi,
                                  const float* __restrict__ pl,
                                  const float* __restrict__ ti,
                                  const float* __restrict__ tp) {
  RowData d;
  const float4* ppi = (const float4*)(pi + base + i0);
  const float4* ppl = (const float4*)(pl + base + i0);
  const float4* pti = (const float4*)(ti + base + i0);
  const float4* ptp = (const float4*)(tp + base + i0);
  d.pi0 = ppi[0]; d.pi1 = ppi[1];
  d.pl0 = ppl[0]; d.pl1 = ppl[1];
  d.ti0 = pti[0]; d.ti1 = pti[1];
  d.tp0 = ptp[0]; d.tp1 = ptp[1];
  return d;
}

__device__ inline void computeRow(const RowData& dta, int bid, bool act,
                                  float* __restrict__ pb) {
  __shared__ float red[4][8];
  __shared__ float bc[2];
  __shared__ float wtot[4];

  const int tid = threadIdx.x;
  const int lane = tid & 63;
  const int wid = tid >> 6;
  const int i0 = tid * 8;

  float a[8], b[8];
  float s_bce = 0.f, s_sq = 0.f, s_iw = 0.f, la = 0.f, lb = 0.f;

  if (act) {
    float xpi[8] = {dta.pi0.x, dta.pi0.y, dta.pi0.z, dta.pi0.w,
                    dta.pi1.x, dta.pi1.y, dta.pi1.z, dta.pi1.w};
    float xpl[8] = {dta.pl0.x, dta.pl0.y, dta.pl0.z, dta.pl0.w,
                    dta.pl1.x, dta.pl1.y, dta.pl1.z, dta.pl1.w};
    float xti[8] = {dta.ti0.x, dta.ti0.y, dta.ti0.z, dta.ti0.w,
                    dta.ti1.x, dta.ti1.y, dta.ti1.z, dta.ti1.w};
    float xtp[8] = {dta.tp0.x, dta.tp0.y, dta.tp0.z, dta.tp0.w,
                    dta.tp1.x, dta.tp1.y, dta.tp1.z, dta.tp1.w};
#pragma unroll
    for (int j = 0; j < 8; ++j) {
      const float x = xpl[j];
      const float y = xtp[j];
      const float em = __expf(-fabsf(x));
      const float bce = fmaxf(x, 0.f) - x * y + __logf(1.f + em);
      const bool pos = (y > 0.5f);
      s_bce += bce * (pos ? POS_W : 1.f);
      const float d = xpi[j] - xti[j];
      if (pos) { s_sq = fmaf(d, d, s_sq); s_iw += 1.f; }
      const float inv = __builtin_amdgcn_rcpf(1.f + em);
      const float sig = (x >= 0.f) ? inv : em * inv;
      const float av = fmaxf(xpi[j], 0.f) * sig;
      const float bv = xti[j] * y;
      a[j] = av; b[j] = bv;
      la += av; lb += bv;
    }
  } else {
#pragma unroll
    for (int j = 0; j < 8; ++j) { a[j] = 0.f; b[j] = 0.f; }
  }

  float v0 = waveReduce(la);
  float v1 = waveReduce(lb);
  float v2 = waveReduce(s_bce);
  float v3 = waveReduce(s_sq);
  float v4 = waveReduce(s_iw);
  if (lane == 0) {
    red[wid][0] = v0; red[wid][1] = v1; red[wid][2] = v2;
    red[wid][3] = v3; red[wid][4] = v4;
  }
  ldsBarrier();
  if (tid == 0) {
    const float s1  = red[0][0] + red[1][0] + red[2][0] + red[3][0];
    const float st1 = red[0][1] + red[1][1] + red[2][1] + red[3][1];
    bc[0] = s1; bc[1] = st1;
    pb[0 * PB_STRIDE + bid] = red[0][2] + red[1][2] + red[2][2] + red[3][2];
    pb[1 * PB_STRIDE + bid] = red[0][3] + red[1][3] + red[2][3] + red[3][3];
    pb[2 * PB_STRIDE + bid] = red[0][4] + red[1][4] + red[2][4] + red[3][4];
  }
  ldsBarrier();
  const float s1 = bc[0], st1 = bc[1];

  const float s2 = s1 / (s1 + EPSF);
  const float scaleP = 1.f / ((s1 + EPSF) * (s2 + EPSF));
  const float st2 = st1 / (st1 + EPSF);
  const float scaleQ = 1.f / ((st1 + EPSF) * (st2 + EPSF));

  float run = 0.f;
#pragma unroll
  for (int j = 0; j < 8; ++j) {
    run += a[j] * scaleP - b[j] * scaleQ;
    a[j] = run;
  }

  float sc = run;
#pragma unroll
  for (int off = 1; off < 64; off <<= 1) {
    const float t = __shfl_up(sc, off, 64);
    if (lane >= off) sc += t;
  }
  if (lane == 63) wtot[wid] = sc;
  ldsBarrier();
  float woff = 0.f;
#pragma unroll
  for (int w = 0; w < 4; ++w) woff += (w < wid) ? wtot[w] : 0.f;
  const float excl = sc - run + woff;

  float labs = 0.f;
#pragma unroll
  for (int j = 0; j < 8; ++j) {
    if (i0 + j < MZ - 1) labs += fabsf(excl + a[j]);
  }
  labs = waveReduce(labs);
  if (lane == 0) red[wid][0] = labs;
  ldsBarrier();
  if (tid == 0) {
    const float t = red[0][0] + red[1][0] + red[2][0] + red[3][0];
    const float w1 = t * (1.f / (1999.0f + EPSF));
    const float psum = s2 / (s2 + EPSF);
    const float qsum = st2 / (st2 + EPSF);
    const float valid = (qsum > EPSF) ? 1.f : 0.f;
    const float per = (psum > EPSF) ? w1 : 1.f;
    pb[3 * PB_STRIDE + bid] = per * valid;
    pb[4 * PB_STRIDE + bid] = valid;
  }
  // WAR fence: next row's red/bc/wtot writes must not pass tid0's reads above
  ldsBarrier();
}

__device__ inline void rowPersistent(int blk,
                                     const float* __restrict__ pi,
                                     const float* __restrict__ pl,
                                     const float* __restrict__ ti,
                                     const float* __restrict__ tp,
                                     float* __restrict__ pb) {
  const int i0 = threadIdx.x * 8;
  const bool act = (i0 + 8 <= MZ);  // MZ=2000: threads 0..249
  const int row0 = blk * ROWS_PER_BLOCK;

  RowData A = act ? loadRow((long)row0 * MZ, i0, pi, pl, ti, tp) : zeroRow();
#pragma unroll
  for (int i = 0; i < ROWS_PER_BLOCK - 1; ++i) {
    // prefetch next row BEFORE computing current; ldsBarrier (no vmcnt drain)
    // keeps these loads in flight under computeRow's barriers
    RowData B = act ? loadRow((long)(row0 + i + 1) * MZ, i0, pi, pl, ti, tp)
                    : zeroRow();
    computeRow(A, row0 + i, act, pb);
    A = B;
  }
  computeRow(A, row0 + ROWS_PER_BLOCK - 1, act, pb);
}

__device__ inline void morganPersistent(int mbid,
                                        const float* __restrict__ x,
                                        const int* __restrict__ y,
                                        float* __restrict__ pbm) {
  __shared__ float mred[4];
  const long stride = (long)MG_BLOCKS * 256;
  float ls = 0.f;
  long i = (long)mbid * 256 + threadIdx.x;
#pragma unroll 4
  for (int it = 0; it < MG_ITERS; ++it, i += stride) {
    const float4 xv = ((const float4*)x)[i];
    const int4 yv = ((const int4*)y)[i];
    ls += bceFast(xv.x, (float)yv.x);
    ls += bceFast(xv.y, (float)yv.y);
    ls += bceFast(xv.z, (float)yv.z);
    ls += bceFast(xv.w, (float)yv.w);
  }
  ls = waveReduce(ls);
  const int lane = threadIdx.x & 63, wid = threadIdx.x >> 6;
  if (lane == 0) mred[wid] = ls;
  ldsBarrier();
  if (threadIdx.x == 0)
    pbm[mbid] = mred[0] + mred[1] + mred[2] + mred[3];
}

// 1536 blocks: groups of 3 = 2 row-blocks + 1 morgan-block (XCD-balanced mix)
__global__ __launch_bounds__(256) void fused_kernel(
    const float* __restrict__ pi, const float* __restrict__ pl,
    const float* __restrict__ ti, const float* __restrict__ tp,
    const float* __restrict__ mx, const int* __restrict__ my,
    float* __restrict__ ws) {
  const int q = blockIdx.x / 3;
  const int r = blockIdx.x % 3;
  if (r < 2) {
    rowPersistent(q * 2 + r, pi, pl, ti, tp, ws);
  } else {
    morganPersistent(q, mx, my, ws + PBM_OFF);
  }
}

__global__ __launch_bounds__(1024) void reduce_finalize_kernel(
    const float* __restrict__ ws, float* __restrict__ out) {
  __shared__ double red[16][8];
  const int tid = threadIdx.x;
  const int lane = tid & 63, wid = tid >> 6;

  double acc[6] = {0, 0, 0, 0, 0, 0};
#pragma unroll
  for (int k = 0; k < 5; ++k) {
    const float4* v = (const float4*)(ws + k * PB_STRIDE);
    for (int i = tid; i < BB / 4; i += 1024) {
      const float4 f = v[i];
      acc[k] += (double)f.x + (double)f.y + (double)f.z + (double)f.w;
    }
  }
  {
    const float4* v = (const float4*)(ws + PBM_OFF);
    for (int i = tid; i < MG_BLOCKS / 4; i += 1024) {
      const float4 f = v[i];
      acc[5] += (double)f.x + (double)f.y + (double)f.z + (double)f.w;
    }
  }

#pragma unroll
  for (int k = 0; k < 6; ++k) acc[k] = waveReduceD(acc[k]);
  if (lane == 0) {
#pragma unroll
    for (int k = 0; k < 6; ++k) red[wid][k] = acc[k];
  }
  __syncthreads();
  if (tid == 0) {
    double t[6];
#pragma unroll
    for (int k = 0; k < 6; ++k) {
      double s = 0.0;
      for (int w = 0; w < 16; ++w) s += red[w][k];
      t[k] = s;
    }
    const double prob = t[0] / ((double)BB * (double)MZ);
    const double inten = t[1] / (t[2] + (double)EPSF);
    const double nv = t[4];
    const double ws_loss = (nv > 0.0) ? (t[3] / fmax(nv, 1.0)) : 0.0;
    const double morgan = t[5] / ((double)BB * (double)NF);
    double tot = (double)W_PROB * prob + (double)W_INT * inten +
                 (double)W_WS * ws_loss + (double)W_MORGAN * morgan;
    float r = (float)tot;
    if (isnan(r) || isinf(r)) r = 100000.0f;
    out[0] = r;
  }
}

extern "C" void kernel_launch(void* const* d_in, const int* in_sizes, int n_in,
                              void* d_out, int out_size, void* d_ws, size_t ws_size,
                              hipStream_t stream) {
  const float* pred_int = (const float*)d_in[0];
  const float* pred_pl  = (const float*)d_in[1];
  const float* pred_mg  = (const float*)d_in[2];
  const float* true_int = (const float*)d_in[3];
  const float* true_pr  = (const float*)d_in[4];
  const int*   true_mg  = (const int*)d_in[5];
  float* ws = (float*)d_ws;

  fused_kernel<<<ROW_BLOCKS + MG_BLOCKS, 256, 0, stream>>>(
      pred_int, pred_pl, true_int, true_pr, pred_mg, true_mg, ws);
  reduce_finalize_kernel<<<1, 1024, 0, stream>>>(ws, (float*)d_out);
}